// Round 6
// baseline (163.491 us; speedup 1.0000x reference)
//
#include <hip/hip_runtime.h>

#define B 8
#define N 1024
#define E 10
#define GP 44                        // 4 emb rows packed in 44 floats (40 data + 4 pad)
#define EMB_FLOATS (256 * GP)        // 11264 floats per batch
#define EMB_F4 (EMB_FLOATS / 4)      // 2816 float4 per batch

// ---------------------------------------------------------------------------
// K1: base + emb0 via exact relu-collapse:
//   sum_i relu(w[i,j]*c) = c>0 ? c*sum_i max(w,0) : (-c)*sum_i max(-w,0)
//   256 blocks (8 b x 32 col-slices of 32) x 512 thr. One 32 MB HBM pass,
//   float4 reads (1 KB/wave-instruction). Also zeroes qsum + counter.
// ---------------------------------------------------------------------------
__global__ __launch_bounds__(512) void k_base(
    const float* __restrict__ W, const float* __restrict__ features,
    const float* __restrict__ w_sel, const float* __restrict__ w_nbw,
    const float* __restrict__ w_ew, float* __restrict__ base,
    float* __restrict__ emb0, float* __restrict__ qsum)
{
    __shared__ float redP[64][32];
    __shared__ float redN[64][32];
    __shared__ float scol[2][32];
    int bx = blockIdx.x, tid = threadIdx.x;
    int b = bx >> 5, c0 = (bx & 31) * 32;
    int c4 = (tid & 7) * 4;          // float4 col group within slice
    int rg = tid >> 3;               // 64 row-groups x 16 rows
    const float* wp = W + ((size_t)b * N + rg * 16) * N + c0 + c4;
    float4 sp = {0.f, 0.f, 0.f, 0.f}, sn = {0.f, 0.f, 0.f, 0.f};
#pragma unroll
    for (int i = 0; i < 16; ++i) {
        float4 w = *(const float4*)(wp + (size_t)i * N);
        sp.x += fmaxf(w.x, 0.f); sn.x += fmaxf(-w.x, 0.f);
        sp.y += fmaxf(w.y, 0.f); sn.y += fmaxf(-w.y, 0.f);
        sp.z += fmaxf(w.z, 0.f); sn.z += fmaxf(-w.z, 0.f);
        sp.w += fmaxf(w.w, 0.f); sn.w += fmaxf(-w.w, 0.f);
    }
    *(float4*)&redP[rg][c4] = sp;
    *(float4*)&redN[rg][c4] = sn;
    __syncthreads();
    if (tid < 64) {
        int cc = tid & 31;
        const float* rp = (tid < 32) ? &redP[0][0] : &redN[0][0];
        float t = 0.f;
#pragma unroll 8
        for (int g = 0; g < 64; ++g) t += rp[g * 32 + cc];
        scol[tid >> 5][cc] = t;
    }
    __syncthreads();
    if (tid < 32 * E) {
        int cc = tid / E, f = tid % E;
        float spc = scol[0][cc], snc = scol[1][cc];
        float acc = features[(b << 10) + c0 + cc] * w_sel[f];
#pragma unroll
        for (int e = 0; e < E; ++e) {
            float c = w_ew[e];
            float se = (c > 0.f) ? c * spc : (-c) * snc;
            acc += w_nbw[f * E + e] * se;
        }
        int row = c0 + cc;
        base[(size_t)((b << 10) + row) * E + f] = acc;
        emb0[(size_t)b * EMB_FLOATS + (row >> 2) * GP + (row & 3) * E + f] =
            fmaxf(acc, 0.f);
    }
    // zero qsum[8] (floats) + counter[8] (ints) — contiguous, 0-bits for both
    if (bx == 0 && tid < 16) ((float*)qsum)[tid] = 0.f;
}

// ---------------------------------------------------------------------------
// K2: one iteration: v = A @ emb; out = relu(base + v @ Wp^T).
//   512 blocks (8 b x 64 tiles of 16 rows) x 256 thr (4 waves, ~2-3 blocks/CU).
//   Thread (m=tid>>6, s=tid&63): rows i0+m+4k (k<4), cols 4s+q+256c (q<4,c<4).
//   A -> 64 registers via 16 coalesced float4 loads (L3-hot after iter 0).
//   Whole-batch emb (44 KB, group-padded) staged by decoupled float4 copy.
//   FINAL: writes compact emb_out, q-dact partials into qv, qsum atomic, and
//   the LAST block per batch (device-fence fan-in) adds qsum to its batch's qv.
// ---------------------------------------------------------------------------
template <int FINAL>
__global__ __launch_bounds__(256) void k_iter(
    const float* __restrict__ A, const float* __restrict__ ein,
    const float* __restrict__ base, const float* __restrict__ Wp,
    const float* __restrict__ w_reduc, const float* __restrict__ w_all,
    const float* __restrict__ w_act, float* __restrict__ eout,
    float* __restrict__ emb_out, float* __restrict__ qv,
    float* __restrict__ qsum, int* __restrict__ counter)
{
    __shared__ float4 EmS[EMB_F4];        // 45056 B
    __shared__ float vred[4][8][4 * E];   // 5120 B
    __shared__ float WpS[E * E];
    __shared__ float gaS[E], gactS[E];
    __shared__ float vS[16 * E], qS[16 * E], qrow[16];
    __shared__ int lastFlag;

    int bx = blockIdx.x, tid = threadIdx.x;
    int b = bx >> 6, tile = bx & 63;
    int i0 = tile * 16;
    int m = tid >> 6;     // wave: rows i0 + m + 4k
    int s = tid & 63;     // lane: cols 4s + q + 256c

    // A tile -> registers (16 independent coalesced float4 loads)
    float Arf[4][4][4];
    {
        const float* Ab = A + ((size_t)(b * N) + i0 + m) * N + 4 * s;
#pragma unroll
        for (int k = 0; k < 4; ++k)
#pragma unroll
            for (int c = 0; c < 4; ++c) {
                float4 t = *(const float4*)(Ab + (size_t)(4 * k) * N + 256 * c);
                Arf[k][c][0] = t.x; Arf[k][c][1] = t.y;
                Arf[k][c][2] = t.z; Arf[k][c][3] = t.w;
            }
    }

    if (tid < E * E) WpS[tid] = Wp[tid];
    if (FINAL && tid < E) {
        float sa = 0.f, sc = 0.f;
#pragma unroll
        for (int k = 0; k < E; ++k) {
            sa += w_reduc[k] * w_all[k * E + tid];
            sc += w_reduc[E + k] * w_act[k * E + tid];
        }
        gaS[tid] = sa;
        gactS[tid] = sc;
    }

    // stage whole-batch emb: 11 decoupled float4 loads, then 11 ds_writes
    {
        const float4* src = (const float4*)ein + (size_t)b * EMB_F4;
        float4 tmp[11];
#pragma unroll
        for (int t = 0; t < 11; ++t) tmp[t] = src[tid + 256 * t];
#pragma unroll
        for (int t = 0; t < 11; ++t) EmS[tid + 256 * t] = tmp[t];
    }
    __syncthreads();

    float acc[4][E];
#pragma unroll
    for (int k = 0; k < 4; ++k)
#pragma unroll
        for (int e = 0; e < E; ++e) acc[k][e] = 0.f;

#pragma unroll
    for (int c = 0; c < 4; ++c) {
        float4 g4[10];
        const float4* gp = EmS + (size_t)(s + 64 * c) * (GP / 4);
#pragma unroll
        for (int t = 0; t < 10; ++t) g4[t] = gp[t];
        const float* g40 = (const float*)g4;
#pragma unroll
        for (int q = 0; q < 4; ++q)
#pragma unroll
            for (int k = 0; k < 4; ++k) {
                float a = Arf[k][c][q];
#pragma unroll
                for (int e = 0; e < E; ++e)
                    acc[k][e] += a * g40[q * E + e];
            }
    }

    // reduce 64 lanes -> 8 partials per wave (masks 1,2,4)
#pragma unroll
    for (int mask = 1; mask <= 4; mask <<= 1)
#pragma unroll
        for (int k = 0; k < 4; ++k)
#pragma unroll
            for (int e = 0; e < E; ++e)
                acc[k][e] += __shfl_xor(acc[k][e], mask, 64);
    if ((s & 7) == 0)
#pragma unroll
        for (int k = 0; k < 4; ++k)
#pragma unroll
            for (int e = 0; e < E; ++e)
                vred[m][s >> 3][k * E + e] = acc[k][e];
    __syncthreads();

    if (tid < 16 * E) {
        int r = tid / E, f = tid % E;
        int mm = r & 3, kk = r >> 2;
        float v[E];
#pragma unroll
        for (int e = 0; e < E; ++e) {
            float t = 0.f;
#pragma unroll
            for (int g = 0; g < 8; ++g) t += vred[mm][g][kk * E + e];
            v[e] = t;
        }
        float d = 0.f;
#pragma unroll
        for (int e = 0; e < E; ++e) d += v[e] * WpS[f * E + e];
        size_t gi = (size_t)((b << 10) + i0 + r);
        float r_out = fmaxf(base[gi * E + f] + d, 0.f);
        if (FINAL) {
            emb_out[gi * E + f] = r_out;
            vS[tid] = r_out * gactS[f];
            qS[tid] = r_out * gaS[f];
        } else {
            int grow = i0 + r;
            eout[(size_t)b * EMB_FLOATS + (grow >> 2) * GP + (grow & 3) * E + f] = r_out;
        }
    }
    if (FINAL) {
        __syncthreads();
        if (tid < 16) {
            float da = 0.f, dg = 0.f;
#pragma unroll
            for (int f = 0; f < E; ++f) {
                da += vS[tid * E + f];
                dg += qS[tid * E + f];
            }
            qv[(b << 10) + i0 + tid] = da;   // dact partial (S added by last block)
            qrow[tid] = dg;
        }
        __syncthreads();
        if (tid == 0) {
            float t = 0.f;
#pragma unroll
            for (int r = 0; r < 16; ++r) t += qrow[r];
            atomicAdd(&qsum[b], t);
            __threadfence();                  // release: qv stores + qsum visible
            int old = atomicAdd(&counter[b], 1);
            lastFlag = (old == 63) ? 1 : 0;
        }
        __syncthreads();
        if (lastFlag) {                       // last block of this batch
            __threadfence();                  // acquire: invalidate stale L1/L2
            float S = atomicAdd(&qsum[b], 0.f);   // read at coherent point
#pragma unroll
            for (int k = 0; k < 4; ++k) {
                int idx = (b << 10) + tid + 256 * k;
                qv[idx] += S;
            }
        }
    }
}

extern "C" void kernel_launch(void* const* d_in, const int* in_sizes, int n_in,
                              void* d_out, int out_size, void* d_ws, size_t ws_size,
                              hipStream_t stream) {
    const float* features  = (const float*)d_in[0];
    const float* W         = (const float*)d_in[1];
    const float* adjacency = (const float*)d_in[2];
    const float* w_sel     = (const float*)d_in[3];
    const float* w_pri     = (const float*)d_in[4];
    const float* w_nbw     = (const float*)d_in[5];
    const float* w_ew      = (const float*)d_in[6];
    const float* w_reduc   = (const float*)d_in[7];
    const float* w_all     = (const float*)d_in[8];
    const float* w_act     = (const float*)d_in[9];

    float* out     = (float*)d_out;
    float* qv      = out;              // B*N
    float* emb_out = out + B * N;      // B*N*E

    float* ws      = (float*)d_ws;
    float* eA      = ws;                              // B*EMB_FLOATS (group-padded)
    float* eB      = eA + (size_t)B * EMB_FLOATS;
    float* base    = eB + (size_t)B * EMB_FLOATS;     // B*N*E compact
    float* qsum    = base + (size_t)B * N * E;        // 8 floats
    int*   counter = (int*)(qsum + B);                // 8 ints (zeroed by k_base)

    k_base<<<256, 512, 0, stream>>>(W, features, w_sel, w_nbw, w_ew,
                                    base, eA, qsum);
    // ref iter 1 (emb=0) == relu(base) == eA; 4 remaining iterations:
    k_iter<0><<<512, 256, 0, stream>>>(adjacency, eA, base, w_pri, w_reduc,
                                       w_all, w_act, eB, emb_out, qv, qsum, counter);
    k_iter<0><<<512, 256, 0, stream>>>(adjacency, eB, base, w_pri, w_reduc,
                                       w_all, w_act, eA, emb_out, qv, qsum, counter);
    k_iter<0><<<512, 256, 0, stream>>>(adjacency, eA, base, w_pri, w_reduc,
                                       w_all, w_act, eB, emb_out, qv, qsum, counter);
    k_iter<1><<<512, 256, 0, stream>>>(adjacency, eB, base, w_pri, w_reduc,
                                       w_all, w_act, eA, emb_out, qv, qsum, counter);
}

// Round 7
// 155.284 us; speedup vs baseline: 1.0529x; 1.0529x over previous
//
#include <hip/hip_runtime.h>

#define B 8
#define N 1024
#define E 10
#define GP 44                        // 4 emb rows packed in 44 floats (40 data + 4 pad)
#define EMB_FLOATS (256 * GP)        // 11264 floats per batch
#define EMB_F4 (EMB_FLOATS / 4)      // 2816 float4 per batch

// ---------------------------------------------------------------------------
// K1: base + emb0 via exact relu-collapse:
//   sum_i relu(w[i,j]*c) = c>0 ? c*sum_i max(w,0) : (-c)*sum_i max(-w,0)
//   256 blocks (8 b x 32 col-slices of 32) x 512 thr. One 32 MB HBM pass,
//   float4 reads (1 KB per wave-instruction). Also zeroes qsum.
// ---------------------------------------------------------------------------
__global__ __launch_bounds__(512) void k_base(
    const float* __restrict__ W, const float* __restrict__ features,
    const float* __restrict__ w_sel, const float* __restrict__ w_nbw,
    const float* __restrict__ w_ew, float* __restrict__ base,
    float* __restrict__ emb0, float* __restrict__ qsum)
{
    __shared__ float redP[64][32];
    __shared__ float redN[64][32];
    __shared__ float scol[2][32];
    int bx = blockIdx.x, tid = threadIdx.x;
    int b = bx >> 5, c0 = (bx & 31) * 32;
    int c4 = (tid & 7) * 4;          // float4 col group within 32-col slice
    int rg = tid >> 3;               // 64 row-groups x 16 rows
    const float* wp = W + ((size_t)b * N + rg * 16) * N + c0 + c4;
    float4 sp = {0.f, 0.f, 0.f, 0.f}, sn = {0.f, 0.f, 0.f, 0.f};
#pragma unroll
    for (int i = 0; i < 16; ++i) {
        float4 w = *(const float4*)(wp + (size_t)i * N);
        sp.x += fmaxf(w.x, 0.f); sn.x += fmaxf(-w.x, 0.f);
        sp.y += fmaxf(w.y, 0.f); sn.y += fmaxf(-w.y, 0.f);
        sp.z += fmaxf(w.z, 0.f); sn.z += fmaxf(-w.z, 0.f);
        sp.w += fmaxf(w.w, 0.f); sn.w += fmaxf(-w.w, 0.f);
    }
    *(float4*)&redP[rg][c4] = sp;
    *(float4*)&redN[rg][c4] = sn;
    __syncthreads();
    if (tid < 64) {
        int cc = tid & 31;
        const float* rp = (tid < 32) ? &redP[0][0] : &redN[0][0];
        float t = 0.f;
#pragma unroll 8
        for (int g = 0; g < 64; ++g) t += rp[g * 32 + cc];
        scol[tid >> 5][cc] = t;
    }
    __syncthreads();
    if (tid < 32 * E) {
        int cc = tid / E, f = tid % E;
        float spc = scol[0][cc], snc = scol[1][cc];
        float acc = features[(b << 10) + c0 + cc] * w_sel[f];
#pragma unroll
        for (int e = 0; e < E; ++e) {
            float c = w_ew[e];
            float se = (c > 0.f) ? c * spc : (-c) * snc;
            acc += w_nbw[f * E + e] * se;
        }
        int row = c0 + cc;
        base[(size_t)((b << 10) + row) * E + f] = acc;
        emb0[(size_t)b * EMB_FLOATS + (row >> 2) * GP + (row & 3) * E + f] =
            fmaxf(acc, 0.f);
    }
    if (bx == 0 && tid < B) qsum[tid] = 0.f;
}

// ---------------------------------------------------------------------------
// K2: one iteration: v = A @ emb; out = relu(base + v @ Wp^T).
//   512 blocks (8 b x 64 tiles of 16 rows) x 256 thr (4 waves, ~3 blocks/CU).
//   Thread (m=tid>>6, s=tid&63): rows i0+m+4k (k<4), cols 4s+q+256c (q<4,c<4).
//   A -> 64 registers via 16 coalesced float4 loads (L3-hot after iter 0).
//   Whole-batch emb (44 KB, group-padded) staged by decoupled float4 copy.
//   FINAL: writes compact emb_out, per-tile dact partials into qv, qsum atomic.
//   (No fence/fan-in in FINAL — measured slower; separate k_q is cheaper.)
// ---------------------------------------------------------------------------
template <int FINAL>
__global__ __launch_bounds__(256) void k_iter(
    const float* __restrict__ A, const float* __restrict__ ein,
    const float* __restrict__ base, const float* __restrict__ Wp,
    const float* __restrict__ w_reduc, const float* __restrict__ w_all,
    const float* __restrict__ w_act, float* __restrict__ eout,
    float* __restrict__ emb_out, float* __restrict__ qv,
    float* __restrict__ qsum)
{
    __shared__ float4 EmS[EMB_F4];        // 45056 B
    __shared__ float vred[4][8][4 * E];   // 5120 B
    __shared__ float WpS[E * E];
    __shared__ float gaS[E], gactS[E];
    __shared__ float vS[16 * E], qS[16 * E], qrow[16];

    int bx = blockIdx.x, tid = threadIdx.x;
    int b = bx >> 6, tile = bx & 63;
    int i0 = tile * 16;
    int m = tid >> 6;     // wave: rows i0 + m + 4k
    int s = tid & 63;     // lane: cols 4s + q + 256c

    // A tile -> registers (16 independent coalesced float4 loads)
    float Arf[4][4][4];
    {
        const float* Ab = A + ((size_t)(b * N) + i0 + m) * N + 4 * s;
#pragma unroll
        for (int k = 0; k < 4; ++k)
#pragma unroll
            for (int c = 0; c < 4; ++c) {
                float4 t = *(const float4*)(Ab + (size_t)(4 * k) * N + 256 * c);
                Arf[k][c][0] = t.x; Arf[k][c][1] = t.y;
                Arf[k][c][2] = t.z; Arf[k][c][3] = t.w;
            }
    }

    if (tid < E * E) WpS[tid] = Wp[tid];
    if (FINAL && tid < E) {
        float sa = 0.f, sc = 0.f;
#pragma unroll
        for (int k = 0; k < E; ++k) {
            sa += w_reduc[k] * w_all[k * E + tid];
            sc += w_reduc[E + k] * w_act[k * E + tid];
        }
        gaS[tid] = sa;
        gactS[tid] = sc;
    }

    // stage whole-batch emb: 11 decoupled float4 loads, then 11 ds_writes
    {
        const float4* src = (const float4*)ein + (size_t)b * EMB_F4;
        float4 tmp[11];
#pragma unroll
        for (int t = 0; t < 11; ++t) tmp[t] = src[tid + 256 * t];
#pragma unroll
        for (int t = 0; t < 11; ++t) EmS[tid + 256 * t] = tmp[t];
    }
    __syncthreads();

    float acc[4][E];
#pragma unroll
    for (int k = 0; k < 4; ++k)
#pragma unroll
        for (int e = 0; e < E; ++e) acc[k][e] = 0.f;

#pragma unroll
    for (int c = 0; c < 4; ++c) {
        float4 g4[10];
        const float4* gp = EmS + (size_t)(s + 64 * c) * (GP / 4);
#pragma unroll
        for (int t = 0; t < 10; ++t) g4[t] = gp[t];
        const float* g40 = (const float*)g4;
#pragma unroll
        for (int q = 0; q < 4; ++q)
#pragma unroll
            for (int k = 0; k < 4; ++k) {
                float a = Arf[k][c][q];
#pragma unroll
                for (int e = 0; e < E; ++e)
                    acc[k][e] += a * g40[q * E + e];
            }
    }

    // reduce 64 lanes -> 8 partials per wave (masks 1,2,4)
#pragma unroll
    for (int mask = 1; mask <= 4; mask <<= 1)
#pragma unroll
        for (int k = 0; k < 4; ++k)
#pragma unroll
            for (int e = 0; e < E; ++e)
                acc[k][e] += __shfl_xor(acc[k][e], mask, 64);
    if ((s & 7) == 0)
#pragma unroll
        for (int k = 0; k < 4; ++k)
#pragma unroll
            for (int e = 0; e < E; ++e)
                vred[m][s >> 3][k * E + e] = acc[k][e];
    __syncthreads();

    if (tid < 16 * E) {
        int r = tid / E, f = tid % E;
        int mm = r & 3, kk = r >> 2;
        float v[E];
#pragma unroll
        for (int e = 0; e < E; ++e) {
            float t = 0.f;
#pragma unroll
            for (int g = 0; g < 8; ++g) t += vred[mm][g][kk * E + e];
            v[e] = t;
        }
        float d = 0.f;
#pragma unroll
        for (int e = 0; e < E; ++e) d += v[e] * WpS[f * E + e];
        size_t gi = (size_t)((b << 10) + i0 + r);
        float r_out = fmaxf(base[gi * E + f] + d, 0.f);
        if (FINAL) {
            emb_out[gi * E + f] = r_out;
            vS[tid] = r_out * gactS[f];
            qS[tid] = r_out * gaS[f];
        } else {
            int grow = i0 + r;
            eout[(size_t)b * EMB_FLOATS + (grow >> 2) * GP + (grow & 3) * E + f] = r_out;
        }
    }
    if (FINAL) {
        __syncthreads();
        if (tid < 16) {
            float da = 0.f, dg = 0.f;
#pragma unroll
            for (int f = 0; f < E; ++f) {
                da += vS[tid * E + f];
                dg += qS[tid * E + f];
            }
            qv[(b << 10) + i0 + tid] = da;   // dact partial; k_q adds qsum[b]
            qrow[tid] = dg;
        }
        __syncthreads();
        if (tid == 0) {
            float t = 0.f;
#pragma unroll
            for (int r = 0; r < 16; ++r) t += qrow[r];
            atomicAdd(&qsum[b], t);
        }
    }
}

// ---------------------------------------------------------------------------
// K3: qv[g] += qsum[g>>10]  (tiny; cheaper than a fence+fan-in inside FINAL)
// ---------------------------------------------------------------------------
__global__ __launch_bounds__(256) void k_q(float* __restrict__ qv,
                                           const float* __restrict__ qsum) {
    int g = blockIdx.x * 256 + threadIdx.x;
    qv[g] += qsum[g >> 10];
}

extern "C" void kernel_launch(void* const* d_in, const int* in_sizes, int n_in,
                              void* d_out, int out_size, void* d_ws, size_t ws_size,
                              hipStream_t stream) {
    const float* features  = (const float*)d_in[0];
    const float* W         = (const float*)d_in[1];
    const float* adjacency = (const float*)d_in[2];
    const float* w_sel     = (const float*)d_in[3];
    const float* w_pri     = (const float*)d_in[4];
    const float* w_nbw     = (const float*)d_in[5];
    const float* w_ew      = (const float*)d_in[6];
    const float* w_reduc   = (const float*)d_in[7];
    const float* w_all     = (const float*)d_in[8];
    const float* w_act     = (const float*)d_in[9];

    float* out     = (float*)d_out;
    float* qv      = out;              // B*N
    float* emb_out = out + B * N;      // B*N*E

    float* ws   = (float*)d_ws;
    float* eA   = ws;                              // B*EMB_FLOATS (group-padded)
    float* eB   = eA + (size_t)B * EMB_FLOATS;
    float* base = eB + (size_t)B * EMB_FLOATS;     // B*N*E compact
    float* qsum = base + (size_t)B * N * E;        // 8 floats

    k_base<<<256, 512, 0, stream>>>(W, features, w_sel, w_nbw, w_ew,
                                    base, eA, qsum);
    // ref iter 1 (emb=0) == relu(base) == eA; 4 remaining iterations:
    k_iter<0><<<512, 256, 0, stream>>>(adjacency, eA, base, w_pri, w_reduc,
                                       w_all, w_act, eB, emb_out, qv, qsum);
    k_iter<0><<<512, 256, 0, stream>>>(adjacency, eB, base, w_pri, w_reduc,
                                       w_all, w_act, eA, emb_out, qv, qsum);
    k_iter<0><<<512, 256, 0, stream>>>(adjacency, eA, base, w_pri, w_reduc,
                                       w_all, w_act, eB, emb_out, qv, qsum);
    k_iter<1><<<512, 256, 0, stream>>>(adjacency, eB, base, w_pri, w_reduc,
                                       w_all, w_act, nullptr, emb_out, qv, qsum);
    k_q<<<32, 256, 0, stream>>>(qv, qsum);
}